// Round 5
// baseline (405.339 us; speedup 1.0000x reference)
//
#include <hip/hip_runtime.h>
#include <cstdint>
#include <cstddef>

#define M_DIM 4096
#define N_DIM 8192
#define K_DIM 4096

typedef __attribute__((ext_vector_type(4))) int int4v;

// ---------------------------------------------------------------------------
// Pack into MFMA-fragment order (int32 -> int8). R3/R8-verified, identical.
// p = 16-row panel, s = 64-byte kstep, lane l: chunk(p,s) is 1024 B where
// lane l holds row 16p+(l&15), k-bytes s*64 + (l>>4)*16 .. +16.
// ---------------------------------------------------------------------------
__global__ void __launch_bounds__(256) pack_frag(const int* __restrict__ a,
                                                 const int* __restrict__ b,
                                                 unsigned char* __restrict__ pa,
                                                 unsigned char* __restrict__ pb) {
    size_t t = (size_t)blockIdx.x * 256 + threadIdx.x;
    const size_t NA = (size_t)(M_DIM / 16) * (K_DIM / 64) * 64;
    const int* __restrict__ src;
    unsigned char* __restrict__ dst;
    if (t < NA) {
        src = a; dst = pa;
    } else {
        src = b; dst = pb; t -= NA;
    }
    const int l = (int)(t & 63);
    const int s = (int)((t >> 6) & 63);
    const int p = (int)(t >> 12);
    const int* g = src + ((size_t)(16 * p + (l & 15))) * K_DIM + s * 64 + (l >> 4) * 16;
    const int4v* g4 = (const int4v*)g;
    int4v o;
#pragma unroll
    for (int q = 0; q < 4; ++q) {
        int4v v = g4[q];
        o[q] = (v[0] & 0xff) | ((v[1] & 0xff) << 8) | ((v[2] & 0xff) << 16) | (v[3] << 24);
    }
    ((int4v*)dst)[t] = o;
}

// ---------------------------------------------------------------------------
// GEMM: block 128(M) x 256(N), 256 thr = 4 waves, wave tile 64x128,
// mfma_i32_16x16x64_i8, BK=64 — R3's verified geometry/epilogue.
// CHANGE vs R3 (117.6 us, MfmaUtil 53%): INTRA-WAVE fragment pipelining.
// R3's counters showed per-tile time ~= LDS-read + MFMA SUM (2205 vs 2458
// cyc/pair): same-tile ds_read->MFMA dependency serializes the pipes and the
// two co-resident blocks phase-lock. Fix: double-buffered fragment REGISTER
// sets — at iter T the wave runs 32 MFMAs entirely from regs (set T&1) while
// ds_reading tile T+1's fragments into the other set. MFMA(T) depends on
// nothing issued at T, so per-wave time -> max(MFMA, LDS) instead of sum.
//   * 4 LDS buffers (4 x 24 KB = 96 KB) -> 1 block/CU, 1 wave/SIMD,
//     VGPR budget 512 (acc 128 in AGPR + 2 frag sets 96 VGPR fits).
//   * DMA issued 3 tiles ahead; boundary = counted vmcnt(6) + s_barrier:
//     at boundary of T, tile T+2 (issued T-1, one full iter of latency)
//     completes; tile T+3 stays in flight. Reads at iter T+1 target tile
//     T+2 — resident and published by that barrier.
//   * Buffer reuse safety: tile t's frags are read at iter t-1 and consumed
//     by MFMAs at iter t (lgkm-forced before boundary(t)); DMA reusing that
//     buffer (tile t+4) issues at iter t+1, after boundary(t). No race.
//   * Tail: when issues stop (T+3>=NT), boundary wait drains to vmcnt(0).
// Loop unrolled x2 so frag-set indexing is static (no scratch, rule #20).
// ---------------------------------------------------------------------------
__device__ inline void async_copy16(const unsigned char* g, unsigned char* l) {
    __builtin_amdgcn_global_load_lds(
        (const __attribute__((address_space(1))) void*)g,
        (__attribute__((address_space(3))) void*)l,
        16, 0, 0);
}

#define BAR() __builtin_amdgcn_s_barrier()

__global__ void __launch_bounds__(256, 1) gemm_i8(const unsigned char* __restrict__ Ap,
                                                  const unsigned char* __restrict__ Bp,
                                                  const _Float16* __restrict__ arow,
                                                  const _Float16* __restrict__ acol,
                                                  _Float16* __restrict__ Cout) {
    // buffer for tile t at (t&3)*24576: A panels [0,8K), B panels [8K,24K)
    __shared__ __align__(16) unsigned char lds[4 * 24576];

    const int tid  = threadIdx.x;
    const int lane = tid & 63;
    const int wave = tid >> 6;        // 0..3
    const int bn   = blockIdx.x;      // 0..31 (256 cols)
    const int bm   = blockIdx.y;      // 0..31 (128 rows)

    const int pm0 = (wave & 1) * 4;   // A panel base (4 panels = 64 rows)
    const int pn0 = (wave >> 1) * 8;  // B panel base (8 panels = 128 cols)

    // staging: wave w stages A panels {2w,2w+1} (2 chunks) and
    // B panels {4w..4w+3} (4 chunks); 24 chunks = 24 KB per tile per block.
    const unsigned char* ag[2];
    int salo[2];
#pragma unroll
    for (int r = 0; r < 2; ++r) {
        const int p = 2 * wave + r;
        ag[r]   = Ap + (size_t)(bm * 8 + p) * 65536 + lane * 16;
        salo[r] = p * 1024;  // wave-uniform; HW adds lane*16
    }
    const unsigned char* bg[4];
    int sblo[4];
#pragma unroll
    for (int r = 0; r < 4; ++r) {
        const int p = 4 * wave + r;
        bg[r]   = Bp + (size_t)(bn * 16 + p) * 65536 + lane * 16;
        sblo[r] = 8192 + p * 1024;
    }

    const int a_off = pm0 * 1024 + lane * 16;         // + i*1024
    const int b_off = 8192 + pn0 * 1024 + lane * 16;  // + j*1024

    int4v acc[4][8];
#pragma unroll
    for (int i = 0; i < 4; ++i)
#pragma unroll
        for (int j = 0; j < 8; ++j) acc[i][j] = (int4v)0;

    const int NT = K_DIM / 64;  // 64

    // prologue: stage tiles 0,1,2 into buffers 0,1,2 (18 loads)
#pragma unroll
    for (int t = 0; t < 3; ++t) {
        const size_t gk = (size_t)t * 1024;
        const int lo = t * 24576;
#pragma unroll
        for (int r = 0; r < 2; ++r) async_copy16(ag[r] + gk, lds + lo + salo[r]);
#pragma unroll
        for (int r = 0; r < 4; ++r) async_copy16(bg[r] + gk, lds + lo + sblo[r]);
    }
    asm volatile("s_waitcnt vmcnt(6)" ::: "memory");  // tiles 0,1 resident; 2 in flight
    BAR();

    // preload fragment set 0 <- tile 0
    int4v af0[4], bf0[8], af1[4], bf1[8];
#pragma unroll
    for (int i = 0; i < 4; ++i) af0[i] = *(const int4v*)(lds + a_off + i * 1024);
#pragma unroll
    for (int j = 0; j < 8; ++j) bf0[j] = *(const int4v*)(lds + b_off + j * 1024);

#pragma unroll 1
    for (int u = 0; u < NT / 2; ++u) {
        // ================= even iter: T = 2u, MFMA set0, read set1 ==========
        {
            const int T = 2 * u;
            if (T + 3 < NT) {  // issue DMA for tile T+3 into buffer (T+3)&3
                const size_t gk = (size_t)(T + 3) * 1024;
                const int lo = ((T + 3) & 3) * 24576;
#pragma unroll
                for (int r = 0; r < 2; ++r) async_copy16(ag[r] + gk, lds + lo + salo[r]);
#pragma unroll
                for (int r = 0; r < 4; ++r) async_copy16(bg[r] + gk, lds + lo + sblo[r]);
            }
            {  // read tile T+1 fragments -> set1 (T+1 < NT always here)
                const unsigned char* Rb = lds + ((T + 1) & 3) * 24576;
#pragma unroll
                for (int i = 0; i < 4; ++i) af1[i] = *(const int4v*)(Rb + a_off + i * 1024);
#pragma unroll
                for (int j = 0; j < 8; ++j) bf1[j] = *(const int4v*)(Rb + b_off + j * 1024);
            }
            __builtin_amdgcn_s_setprio(1);
#pragma unroll
            for (int i = 0; i < 4; ++i)
#pragma unroll
                for (int j = 0; j < 8; ++j)
                    acc[i][j] = __builtin_amdgcn_mfma_i32_16x16x64_i8(af0[i], bf0[j],
                                                                      acc[i][j], 0, 0, 0);
            __builtin_amdgcn_s_setprio(0);
            if (T + 3 < NT) {
                asm volatile("s_waitcnt vmcnt(6)" ::: "memory");  // T+2 done, T+3 in flight
            } else {
                asm volatile("s_waitcnt vmcnt(0)" ::: "memory");
            }
            BAR();
        }
        // ================= odd iter: T = 2u+1, MFMA set1, read set0 =========
        {
            const int T = 2 * u + 1;
            if (T + 3 < NT) {
                const size_t gk = (size_t)(T + 3) * 1024;
                const int lo = ((T + 3) & 3) * 24576;
#pragma unroll
                for (int r = 0; r < 2; ++r) async_copy16(ag[r] + gk, lds + lo + salo[r]);
#pragma unroll
                for (int r = 0; r < 4; ++r) async_copy16(bg[r] + gk, lds + lo + sblo[r]);
            }
            if (T + 1 < NT) {  // read tile T+1 fragments -> set0
                const unsigned char* Rb = lds + ((T + 1) & 3) * 24576;
#pragma unroll
                for (int i = 0; i < 4; ++i) af0[i] = *(const int4v*)(Rb + a_off + i * 1024);
#pragma unroll
                for (int j = 0; j < 8; ++j) bf0[j] = *(const int4v*)(Rb + b_off + j * 1024);
            }
            __builtin_amdgcn_s_setprio(1);
#pragma unroll
            for (int i = 0; i < 4; ++i)
#pragma unroll
                for (int j = 0; j < 8; ++j)
                    acc[i][j] = __builtin_amdgcn_mfma_i32_16x16x64_i8(af1[i], bf1[j],
                                                                      acc[i][j], 0, 0, 0);
            __builtin_amdgcn_s_setprio(0);
            if (T + 3 < NT) {
                asm volatile("s_waitcnt vmcnt(6)" ::: "memory");
            } else {
                asm volatile("s_waitcnt vmcnt(0)" ::: "memory");
            }
            BAR();
        }
    }

    // --- epilogue: C/D layout col=lane&15, row=(lane>>4)*4+reg (verified)
    const int gcol0 = bn * 256 + pn0 * 16 + (lane & 15);
    float ac8[8];
#pragma unroll
    for (int j = 0; j < 8; ++j) ac8[j] = (float)acol[gcol0 + j * 16];

    const size_t grow0 = (size_t)bm * 128 + pm0 * 16 + (lane >> 4) * 4;
#pragma unroll
    for (int i = 0; i < 4; ++i) {
#pragma unroll
        for (int r = 0; r < 4; ++r) {
            const size_t row = grow0 + i * 16 + r;
            const float ar = (float)arow[row];
            _Float16* outp = Cout + row * (size_t)N_DIM + gcol0;
#pragma unroll
            for (int j = 0; j < 8; ++j) {
                float v = (float)acc[i][j][r] * ar * ac8[j];
                outp[j * 16] = (_Float16)v;
            }
        }
    }
}

// ---------------------------------------------------------------------------
extern "C" void kernel_launch(void* const* d_in, const int* in_sizes, int n_in,
                              void* d_out, int out_size, void* d_ws, size_t ws_size,
                              hipStream_t stream) {
    const int* a = (const int*)d_in[0];             // [M,K] int32 (int8 values)
    const int* b = (const int*)d_in[1];             // [N,K] int32 (int8 values)
    const _Float16* ar = (const _Float16*)d_in[2];  // [M] fp16
    const _Float16* ac = (const _Float16*)d_in[3];  // [N] fp16
    _Float16* out = (_Float16*)d_out;               // [M,N] fp16

    unsigned char* pa = (unsigned char*)d_ws;        // 16 MB
    unsigned char* pb = pa + (size_t)M_DIM * K_DIM;  // 32 MB

    const size_t total_frag = (size_t)(M_DIM / 16 + N_DIM / 16) * (K_DIM / 64) * 64;
    pack_frag<<<(int)(total_frag / 256), 256, 0, stream>>>(a, b, pa, pb);

    dim3 grid(N_DIM / 256, M_DIM / 128);
    gemm_i8<<<grid, 256, 0, stream>>>(pa, pb, ar, ac, out);
}

// Round 6
// 388.759 us; speedup vs baseline: 1.0427x; 1.0427x over previous
//
#include <hip/hip_runtime.h>
#include <cstdint>
#include <cstddef>

#define M_DIM 4096
#define N_DIM 8192
#define K_DIM 4096

typedef __attribute__((ext_vector_type(4))) int int4v;

// ---------------------------------------------------------------------------
// Pack into MFMA-fragment order (int32 -> int8). R3/R8-verified, identical.
// p = 16-row panel, s = 64-byte kstep, lane l: chunk(p,s) is 1024 B where
// lane l holds row 16p+(l&15), k-bytes s*64 + (l>>4)*16 .. +16.
// ---------------------------------------------------------------------------
__global__ void __launch_bounds__(256) pack_frag(const int* __restrict__ a,
                                                 const int* __restrict__ b,
                                                 unsigned char* __restrict__ pa,
                                                 unsigned char* __restrict__ pb) {
    size_t t = (size_t)blockIdx.x * 256 + threadIdx.x;
    const size_t NA = (size_t)(M_DIM / 16) * (K_DIM / 64) * 64;
    const int* __restrict__ src;
    unsigned char* __restrict__ dst;
    if (t < NA) {
        src = a; dst = pa;
    } else {
        src = b; dst = pb; t -= NA;
    }
    const int l = (int)(t & 63);
    const int s = (int)((t >> 6) & 63);
    const int p = (int)(t >> 12);
    const int* g = src + ((size_t)(16 * p + (l & 15))) * K_DIM + s * 64 + (l >> 4) * 16;
    const int4v* g4 = (const int4v*)g;
    int4v o;
#pragma unroll
    for (int q = 0; q < 4; ++q) {
        int4v v = g4[q];
        o[q] = (v[0] & 0xff) | ((v[1] & 0xff) << 8) | ((v[2] & 0xff) << 16) | (v[3] << 24);
    }
    ((int4v*)dst)[t] = o;
}

// ---------------------------------------------------------------------------
// GEMM: block 128(M) x 128(N), 256 thr = 4 waves (2x2), wave tile 64x64,
// mfma_i32_16x16x64_i8, BK=64, acc[4][4] = 64 AGPR.
// SYNTHESIS of R3+R5 post-mortems:
//   * R3 (117.6us, MfmaUtil 53%): occupancy good (2 blocks/CU) but same-tile
//     ds_read->MFMA dependency phase-locked the pipes -> per-tile = SUM.
//   * R5 (166.5us, MfmaUtil 34%): intra-wave register pipelining broke the
//     dependency, but 288 unified regs + 96KB LDS -> 1 wave/SIMD; no TLP to
//     cover boundary waits/barriers.
// This kernel keeps BOTH: smaller wave tile (64x64) fits the fragment
// DOUBLE-BUFFER register sets (2 x 8 b128 = 64 VGPR) + acc (64 AGPR) in
// ~165 unified regs -> 8 waves/CU, AND 4 x 16KB LDS buffers = 64KB ->
// 2 blocks/CU with independent barrier domains.
// Pipeline (R5's hardware-verified scheme, scaled):
//   * iter T: MFMAs run from reg set (T&1) [tile T, loaded last iter];
//     ds_read tile T+1 frags -> other set; issue 4-chunk DMA for tile T+3.
//   * boundary = counted vmcnt(4) + s_barrier: outstanding {T+2:4, T+3:4},
//     completes T+2 (issued at T-1, a full iter of HBM latency) -> iter T+1
//     reads tile T+2 safely. T+3 stays in flight across the barrier.
//   * buffer reuse: DMA(T+3) -> buf (T+3)&3 = (T-1)&3; tile T-1 frags were
//     read at iter T-2, consumed by MFMAs at iter T-1 (lgkm-forced), both
//     before boundary(T-1) barrier which precedes this issue. No race.
//   * tail: issues stop at T=60; waits drain 4 -> 0.
// ---------------------------------------------------------------------------
__device__ inline void async_copy16(const unsigned char* g, unsigned char* l) {
    __builtin_amdgcn_global_load_lds(
        (const __attribute__((address_space(1))) void*)g,
        (__attribute__((address_space(3))) void*)l,
        16, 0, 0);
}

#define BAR() __builtin_amdgcn_s_barrier()

__global__ void __launch_bounds__(256, 2) gemm_i8(const unsigned char* __restrict__ Ap,
                                                  const unsigned char* __restrict__ Bp,
                                                  const _Float16* __restrict__ arow,
                                                  const _Float16* __restrict__ acol,
                                                  _Float16* __restrict__ Cout) {
    // buffer for tile t at (t&3)*16384: A panels [0,8K), B panels [8K,16K)
    __shared__ __align__(16) unsigned char lds[4 * 16384];

    const int tid  = threadIdx.x;
    const int lane = tid & 63;
    const int wave = tid >> 6;        // 0..3
    const int bn   = blockIdx.x;      // 0..63 (128 cols)
    const int bm   = blockIdx.y;      // 0..31 (128 rows)

    const int pm0 = (wave & 1) * 4;   // A panel base (4 panels = 64 rows)
    const int pn0 = (wave >> 1) * 4;  // B panel base (4 panels = 64 cols)

    // staging: wave w stages A panels {2w,2w+1} and B panels {2w,2w+1};
    // 4 chunks = 4 KB per wave per tile (16 KB per tile per block).
    const unsigned char* ag[2];
    int salo[2];
#pragma unroll
    for (int r = 0; r < 2; ++r) {
        const int p = 2 * wave + r;
        ag[r]   = Ap + (size_t)(bm * 8 + p) * 65536 + lane * 16;
        salo[r] = p * 1024;  // wave-uniform; HW adds lane*16
    }
    const unsigned char* bg[2];
    int sblo[2];
#pragma unroll
    for (int r = 0; r < 2; ++r) {
        const int p = 2 * wave + r;
        bg[r]   = Bp + (size_t)(bn * 8 + p) * 65536 + lane * 16;
        sblo[r] = 8192 + p * 1024;
    }

    const int a_off = pm0 * 1024 + lane * 16;         // + i*1024, i=0..3
    const int b_off = 8192 + pn0 * 1024 + lane * 16;  // + j*1024, j=0..3

    int4v acc[4][4];
#pragma unroll
    for (int i = 0; i < 4; ++i)
#pragma unroll
        for (int j = 0; j < 4; ++j) acc[i][j] = (int4v)0;

    const int NT = K_DIM / 64;  // 64

    // prologue: stage tiles 0,1,2 into buffers 0,1,2 (12 loads/wave)
#pragma unroll
    for (int t = 0; t < 3; ++t) {
        const size_t gk = (size_t)t * 1024;
        const int lo = t * 16384;
#pragma unroll
        for (int r = 0; r < 2; ++r) async_copy16(ag[r] + gk, lds + lo + salo[r]);
#pragma unroll
        for (int r = 0; r < 2; ++r) async_copy16(bg[r] + gk, lds + lo + sblo[r]);
    }
    asm volatile("s_waitcnt vmcnt(4)" ::: "memory");  // tiles 0,1 resident; 2 in flight
    BAR();

    // preload fragment set 0 <- tile 0
    int4v af0[4], bf0[4], af1[4], bf1[4];
#pragma unroll
    for (int i = 0; i < 4; ++i) af0[i] = *(const int4v*)(lds + a_off + i * 1024);
#pragma unroll
    for (int j = 0; j < 4; ++j) bf0[j] = *(const int4v*)(lds + b_off + j * 1024);

#pragma unroll 1
    for (int u = 0; u < NT / 2; ++u) {
        // ================= even iter: T = 2u, MFMA set0, read set1 ==========
        {
            const int T = 2 * u;
            if (T + 3 < NT) {  // issue DMA for tile T+3 into buffer (T+3)&3
                const size_t gk = (size_t)(T + 3) * 1024;
                const int lo = ((T + 3) & 3) * 16384;
#pragma unroll
                for (int r = 0; r < 2; ++r) async_copy16(ag[r] + gk, lds + lo + salo[r]);
#pragma unroll
                for (int r = 0; r < 2; ++r) async_copy16(bg[r] + gk, lds + lo + sblo[r]);
            }
            {  // read tile T+1 fragments -> set1 (T+1 < NT always here)
                const unsigned char* Rb = lds + ((T + 1) & 3) * 16384;
#pragma unroll
                for (int i = 0; i < 4; ++i) af1[i] = *(const int4v*)(Rb + a_off + i * 1024);
#pragma unroll
                for (int j = 0; j < 4; ++j) bf1[j] = *(const int4v*)(Rb + b_off + j * 1024);
            }
            __builtin_amdgcn_s_setprio(1);
#pragma unroll
            for (int i = 0; i < 4; ++i)
#pragma unroll
                for (int j = 0; j < 4; ++j)
                    acc[i][j] = __builtin_amdgcn_mfma_i32_16x16x64_i8(af0[i], bf0[j],
                                                                      acc[i][j], 0, 0, 0);
            __builtin_amdgcn_s_setprio(0);
            if (T + 3 < NT) {
                asm volatile("s_waitcnt vmcnt(4)" ::: "memory");  // T+2 done, T+3 in flight
            } else {
                asm volatile("s_waitcnt vmcnt(0)" ::: "memory");
            }
            BAR();
        }
        // ================= odd iter: T = 2u+1, MFMA set1, read set0 =========
        {
            const int T = 2 * u + 1;
            if (T + 3 < NT) {
                const size_t gk = (size_t)(T + 3) * 1024;
                const int lo = ((T + 3) & 3) * 16384;
#pragma unroll
                for (int r = 0; r < 2; ++r) async_copy16(ag[r] + gk, lds + lo + salo[r]);
#pragma unroll
                for (int r = 0; r < 2; ++r) async_copy16(bg[r] + gk, lds + lo + sblo[r]);
            }
            if (T + 1 < NT) {  // read tile T+1 fragments -> set0
                const unsigned char* Rb = lds + ((T + 1) & 3) * 16384;
#pragma unroll
                for (int i = 0; i < 4; ++i) af0[i] = *(const int4v*)(Rb + a_off + i * 1024);
#pragma unroll
                for (int j = 0; j < 4; ++j) bf0[j] = *(const int4v*)(Rb + b_off + j * 1024);
            }
            __builtin_amdgcn_s_setprio(1);
#pragma unroll
            for (int i = 0; i < 4; ++i)
#pragma unroll
                for (int j = 0; j < 4; ++j)
                    acc[i][j] = __builtin_amdgcn_mfma_i32_16x16x64_i8(af1[i], bf1[j],
                                                                      acc[i][j], 0, 0, 0);
            __builtin_amdgcn_s_setprio(0);
            if (T + 3 < NT) {
                asm volatile("s_waitcnt vmcnt(4)" ::: "memory");
            } else {
                asm volatile("s_waitcnt vmcnt(0)" ::: "memory");
            }
            BAR();
        }
    }

    // --- epilogue: C/D layout col=lane&15, row=(lane>>4)*4+reg (verified)
    const int gcol0 = bn * 128 + pn0 * 16 + (lane & 15);
    float ac4[4];
#pragma unroll
    for (int j = 0; j < 4; ++j) ac4[j] = (float)acol[gcol0 + j * 16];

    const size_t grow0 = (size_t)bm * 128 + pm0 * 16 + (lane >> 4) * 4;
#pragma unroll
    for (int i = 0; i < 4; ++i) {
#pragma unroll
        for (int r = 0; r < 4; ++r) {
            const size_t row = grow0 + i * 16 + r;
            const float ar = (float)arow[row];
            _Float16* outp = Cout + row * (size_t)N_DIM + gcol0;
#pragma unroll
            for (int j = 0; j < 4; ++j) {
                float v = (float)acc[i][j][r] * ar * ac4[j];
                outp[j * 16] = (_Float16)v;
            }
        }
    }
}

// ---------------------------------------------------------------------------
extern "C" void kernel_launch(void* const* d_in, const int* in_sizes, int n_in,
                              void* d_out, int out_size, void* d_ws, size_t ws_size,
                              hipStream_t stream) {
    const int* a = (const int*)d_in[0];             // [M,K] int32 (int8 values)
    const int* b = (const int*)d_in[1];             // [N,K] int32 (int8 values)
    const _Float16* ar = (const _Float16*)d_in[2];  // [M] fp16
    const _Float16* ac = (const _Float16*)d_in[3];  // [N] fp16
    _Float16* out = (_Float16*)d_out;               // [M,N] fp16

    unsigned char* pa = (unsigned char*)d_ws;        // 16 MB
    unsigned char* pb = pa + (size_t)M_DIM * K_DIM;  // 32 MB

    const size_t total_frag = (size_t)(M_DIM / 16 + N_DIM / 16) * (K_DIM / 64) * 64;
    pack_frag<<<(int)(total_frag / 256), 256, 0, stream>>>(a, b, pa, pb);

    dim3 grid(N_DIM / 128, M_DIM / 128);
    gemm_i8<<<grid, 256, 0, stream>>>(pa, pb, ar, ac, out);
}